// Round 2
// baseline (1597.883 us; speedup 1.0000x reference)
//
#include <hip/hip_runtime.h>
#include <math.h>

#define SA 68    // stride for [16][64] buffers (pad to kill bank conflicts)
#define SX 132   // stride for [16][128] buffers
#define SF 260   // stride for [16][256] buffer

__device__ __forceinline__ float lrelu_f(float v){ return v > 0.f ? v : 0.01f*v; }
__device__ __forceinline__ float gelu_f(float v){ return 0.5f*v*(1.f + erff(v*0.70710678118654752f)); }

// out[l][d] (d over ND*64 cols) = act( in[l][0..K) @ W[d][0..K)^T + bias ), optional +=
// mapping: l = tid&15 (16 rows), dq = tid>>4 (16 col-quads); lanes sharing dq broadcast weight loads.
template<int ND>
__device__ __forceinline__ void gemm_nd(const float* __restrict__ in, int instride, int K,
                                        const float* __restrict__ W, int wstride,
                                        const float* __restrict__ bias,
                                        float* __restrict__ outp, int outstride,
                                        int tid, int act, bool accum)
{
    const int l  = tid & 15;
    const int dq = tid >> 4;
    float acc[ND][4];
#pragma unroll
    for (int nb = 0; nb < ND; ++nb)
#pragma unroll
        for (int dd = 0; dd < 4; ++dd) acc[nb][dd] = 0.f;
    const float* inrow = in + l*instride;
    for (int k = 0; k < K; k += 4) {
        const float4 a4 = *(const float4*)(inrow + k);
#pragma unroll
        for (int nb = 0; nb < ND; ++nb) {
#pragma unroll
            for (int dd = 0; dd < 4; ++dd) {
                const float4 w4 = *(const float4*)(W + (size_t)(nb*64 + dq*4 + dd)*wstride + k);
                acc[nb][dd] += w4.x*a4.x + w4.y*a4.y + w4.z*a4.z + w4.w*a4.w;
            }
        }
    }
#pragma unroll
    for (int nb = 0; nb < ND; ++nb)
#pragma unroll
        for (int dd = 0; dd < 4; ++dd) {
            const int d = nb*64 + dq*4 + dd;
            float v = acc[nb][dd] + (bias ? bias[d] : 0.f);
            if (act == 1) v = v > 0.f ? v : 0.f;      // relu
            else if (act == 2) v = gelu_f(v);         // gelu
            float* o = outp + l*outstride + d;
            if (accum) *o += v; else *o = v;
        }
}

// LayerNorm over 16 rows x 64 cols; optional roll: source row r -> dest row (r+8)&15
__device__ __forceinline__ void ln16x64(const float* __restrict__ in,
                                        float* __restrict__ outb,
                                        const float* __restrict__ g, const float* __restrict__ bvec,
                                        int tid, bool roll)
{
    const int r = tid >> 4, c0 = (tid & 15) * 4;
    const float4 v = *(const float4*)(in + r*SA + c0);
    float s  = v.x + v.y + v.z + v.w;
    float sq = v.x*v.x + v.y*v.y + v.z*v.z + v.w*v.w;
#pragma unroll
    for (int m = 1; m < 16; m <<= 1) { s += __shfl_xor(s, m, 64); sq += __shfl_xor(sq, m, 64); }
    const float mean = s * (1.f/64.f);
    const float var  = sq * (1.f/64.f) - mean*mean;
    const float rstd = rsqrtf(var + 1e-5f);
    const int rd = roll ? ((r + 8) & 15) : r;
    const float4 gv = *(const float4*)(g + c0);
    const float4 bv = *(const float4*)(bvec + c0);
    float4 o;
    o.x = (v.x-mean)*rstd*gv.x + bv.x;
    o.y = (v.y-mean)*rstd*gv.y + bv.y;
    o.z = (v.z-mean)*rstd*gv.z + bv.z;
    o.w = (v.w-mean)*rstd*gv.w + bv.w;
    *(float4*)(outb + rd*SA + c0) = o;
}

// width-3 conv over L=16, zero pad, leaky-relu. in/out layout [ch][16].
// mode 0: outb = lrelu(conv(in)); mode 1: cxbuf = lrelu(conv(in)) + 2*cxbuf
__device__ __forceinline__ void conv3_lrelu(const float* __restrict__ in,
                                            float* __restrict__ outb,
                                            const float* __restrict__ w, const float* __restrict__ bias,
                                            int tid, int mode, float* __restrict__ cxbuf)
{
    const int o = tid >> 2, l0 = (tid & 3) * 4;
    float acc[4] = {0.f, 0.f, 0.f, 0.f};
    const float* wr0 = w + (size_t)o*64*3;
    for (int i = 0; i < 64; ++i) {
        const float* wr = wr0 + i*3;
        const float w0 = wr[0], w1 = wr[1], w2 = wr[2];
        const float* row = in + i*16 + l0;
        const float xm1 = (l0 == 0)  ? 0.f : row[-1];
        const float x0 = row[0], x1 = row[1], x2 = row[2], x3 = row[3];
        const float xp1 = (l0 == 12) ? 0.f : row[4];
        acc[0] += w0*xm1 + w1*x0 + w2*x1;
        acc[1] += w0*x0  + w1*x1 + w2*x2;
        acc[2] += w0*x1  + w1*x2 + w2*x3;
        acc[3] += w0*x2  + w1*x3 + w2*xp1;
    }
    const float bb = bias[o];
    if (mode == 0) {
#pragma unroll
        for (int j = 0; j < 4; ++j) outb[o*16 + l0 + j] = lrelu_f(acc[j] + bb);
    } else {
#pragma unroll
        for (int j = 0; j < 4; ++j) {
            float* p = cxbuf + o*16 + l0 + j;
            *p = lrelu_f(acc[j] + bb) + 2.f * (*p);
        }
    }
}

__global__ __launch_bounds__(256) void vse_fused(
    const float* __restrict__ x,
    const float* __restrict__ c11_w, const float* __restrict__ c11_b,
    const float* __restrict__ c12_w, const float* __restrict__ c12_b,
    const float* __restrict__ lse1_w, const float* __restrict__ lse1_b,
    const float* __restrict__ lse2_w, const float* __restrict__ lse2_b,
    const float* __restrict__ ln1_g, const float* __restrict__ ln1_b,
    const float* __restrict__ ln2_g, const float* __restrict__ ln2_b,
    const float* __restrict__ mlp1_w, const float* __restrict__ mlp1_b,
    const float* __restrict__ mlp2_w, const float* __restrict__ mlp2_b,
    const float* __restrict__ aln_g, const float* __restrict__ aln_b,
    const float* __restrict__ qkv_w, const float* __restrict__ qkv_b,
    const float* __restrict__ proj_w, const float* __restrict__ proj_b,
    const float* __restrict__ relpos,
    const float* __restrict__ fln_g, const float* __restrict__ fln_b,
    const float* __restrict__ ff1_w, const float* __restrict__ ff1_b,
    const float* __restrict__ ff2_w, const float* __restrict__ ff2_b,
    float* __restrict__ out)
{
    __shared__ float s_xt[16*SX];   // x transposed: [l][c]
    __shared__ float s_yt[16*SX];   // c11 out [l][o]; later: concat buffer for c12
    __shared__ float s_cx[64*16];   // conv branch [c][l]
    __shared__ float s_h [16*SA];
    __shared__ float s_z [16*SA];
    __shared__ float s_a [16*SA];
    __shared__ float s_q [16*SA];
    __shared__ float s_k [16*SA];
    __shared__ float s_v [16*SA];
    __shared__ float s_o [16*SA];
    __shared__ float s_po[16*SA];
    __shared__ float s_att[16*16];
    __shared__ float s_f [16*SF];   // FF hidden / conv temp / final res
    float* const s_t1 = s_f;        // alias: conv temp (disjoint in time)

    const int tid = threadIdx.x;
    const int b = blockIdx.x;
    const float* xb = x + (size_t)b * 2048;

    // ---- load x transposed ----
#pragma unroll
    for (int it = 0; it < 8; ++it) {
        const int idx = tid + it*256;           // = c*16 + l
        const int c = idx >> 4, l = idx & 15;
        s_xt[l*SX + c] = xb[idx];
    }
    __syncthreads();

    // ---- c11 (1x1 conv = 128x128 matmul) + relu ----
    gemm_nd<2>(s_xt, SX, 128, c11_w, 128, c11_b, s_yt, SX, tid, 1, false);
    __syncthreads();

    // ---- split: conv_x [c][l], h [l][d] ----
#pragma unroll
    for (int it = 0; it < 4; ++it) {
        const int idx = tid + it*256;           // 0..1023
        const int i = idx & 63, l = idx >> 6;
        s_cx[i*16 + l] = s_yt[l*SX + i];
        s_h [l*SA + i] = s_yt[l*SX + 64 + i];
    }
    __syncthreads();

    // ---- conv branch: two k=3 convs + leaky relu, then t + 2*conv_x ----
    conv3_lrelu(s_cx, s_t1, lse1_w, lse1_b, tid, 0, nullptr);
    __syncthreads();
    conv3_lrelu(s_t1, nullptr, lse2_w, lse2_b, tid, 1, s_cx);
    __syncthreads();

    // ---- z = LN(h, ln1) ----
    ln16x64(s_h, s_z, ln1_g, ln1_b, tid, false);
    __syncthreads();

    // ---- transformer layers ----
    for (int layer = 0; layer < 2; ++layer) {
        const float* qkv_wl = qkv_w + (size_t)layer * 1536 * 64;
        const float* qkv_bl = qkv_b + layer * 1536;
        const float* proj_wl = proj_w + (size_t)layer * 64 * 512;
        const float* proj_bl = proj_b + layer * 64;
        const float* rel_l = relpos + layer * 8 * 49;

        // a = roll(LN(z, aln), -8)
        ln16x64(s_z, s_a, aln_g + layer*64, aln_b + layer*64, tid, true);
        __syncthreads();

        for (int hh = 0; hh < 8; ++hh) {
            gemm_nd<1>(s_a, SA, 64, qkv_wl + (size_t)(hh*64)*64,        64, qkv_bl + hh*64,        s_q, SA, tid, 0, false);
            gemm_nd<1>(s_a, SA, 64, qkv_wl + (size_t)(512 + hh*64)*64,  64, qkv_bl + 512 + hh*64,  s_k, SA, tid, 0, false);
            gemm_nd<1>(s_a, SA, 64, qkv_wl + (size_t)(1024 + hh*64)*64, 64, qkv_bl + 1024 + hh*64, s_v, SA, tid, 0, false);
            __syncthreads();

            {   // dots + relpos + mask + softmax (thread (i,j) holds one score)
                const int i = tid >> 4, j = tid & 15;
                const float* qi = s_q + i*SA;
                const float* kj = s_k + j*SA;
                float dot = 0.f;
                for (int d0 = 0; d0 < 64; d0 += 4) {
                    const float4 qv = *(const float4*)(qi + d0);
                    const float4 kv = *(const float4*)(kj + d0);
                    dot += qv.x*kv.x + qv.y*kv.y + qv.z*kv.z + qv.w*kv.w;
                }
                float val = dot * 0.125f
                          + rel_l[hh*49 + ((i>>2) - (j>>2) + 3)*7 + ((i&3) - (j&3) + 3)];
                const bool masked = ((hh >= 6) && (((i>>2) < 2) != ((j>>2) < 2)))
                                 || ((hh & 1) && (((i&3) < 2) != ((j&3) < 2)));
                if (masked) val = -1e9f;
                float mx = val;
#pragma unroll
                for (int m = 1; m < 16; m <<= 1) mx = fmaxf(mx, __shfl_xor(mx, m, 64));
                const float e = expf(val - mx);
                float ssum = e;
#pragma unroll
                for (int m = 1; m < 16; m <<= 1) ssum += __shfl_xor(ssum, m, 64);
                s_att[i*16 + j] = e / ssum;
            }
            __syncthreads();

            {   // out_h = attn @ v
                const int l = tid & 15, dq = tid >> 4;
                float a0 = 0.f, a1 = 0.f, a2 = 0.f, a3 = 0.f;
                for (int j = 0; j < 16; ++j) {
                    const float at = s_att[l*16 + j];
                    const float4 v4 = *(const float4*)(s_v + j*SA + dq*4);
                    a0 += at*v4.x; a1 += at*v4.y; a2 += at*v4.z; a3 += at*v4.w;
                }
                float* op = s_o + l*SA + dq*4;
                op[0] = a0; op[1] = a1; op[2] = a2; op[3] = a3;
            }
            __syncthreads();

            // po (+= head's slice of proj); bias on first head
            gemm_nd<1>(s_o, SA, 64, proj_wl + hh*64, 512,
                       (hh == 0) ? proj_bl : nullptr, s_po, SA, tid, 0, hh != 0);
            __syncthreads();
        }

        // z += po
#pragma unroll
        for (int it = 0; it < 4; ++it) {
            const int idx = tid + it*256;
            const int d = idx & 63, l = idx >> 6;
            s_z[l*SA + d] += s_po[l*SA + d];
        }
        __syncthreads();

        // FF block
        ln16x64(s_z, s_a, fln_g + layer*64, fln_b + layer*64, tid, false);
        __syncthreads();
        gemm_nd<4>(s_a, SA, 64, ff1_w + (size_t)layer*256*64, 64, ff1_b + layer*256, s_f, SF, tid, 2, false);
        __syncthreads();
        gemm_nd<1>(s_f, SF, 256, ff2_w + (size_t)layer*64*256, 256, ff2_b + layer*64, s_z, SA, tid, 0, true);
        __syncthreads();
    }

    // ---- h += z; mlp block on h ----
#pragma unroll
    for (int it = 0; it < 4; ++it) {
        const int idx = tid + it*256;
        const int d = idx & 63, l = idx >> 6;
        s_h[l*SA + d] += s_z[l*SA + d];
    }
    __syncthreads();
    ln16x64(s_h, s_a, ln2_g, ln2_b, tid, false);
    __syncthreads();
    gemm_nd<4>(s_a, SA, 64, mlp1_w, 64, mlp1_b, s_f, SF, tid, 2, false);
    __syncthreads();
    gemm_nd<1>(s_f, SF, 256, mlp2_w, 256, mlp2_b, s_h, SA, tid, 0, true);
    __syncthreads();

    // ---- concat [conv_x ; h^T] into s_yt [l][i] ----
#pragma unroll
    for (int it = 0; it < 8; ++it) {
        const int idx = tid + it*256;           // 0..2047
        const int i = idx & 127, l = idx >> 7;
        s_yt[l*SX + i] = (i < 64) ? s_cx[i*16 + l] : s_h[l*SA + (i - 64)];
    }
    __syncthreads();

    // ---- c12 (1x1 conv) -> s_f as res[l][c] ----
    gemm_nd<2>(s_yt, SX, 128, c12_w, 128, c12_b, s_f, SF, tid, 0, false);
    __syncthreads();

    // ---- out = x + res ----
    float* ob = out + (size_t)b * 2048;
#pragma unroll
    for (int it = 0; it < 8; ++it) {
        const int idx = tid + it*256;           // = c*16 + l
        const int c = idx >> 4, l = idx & 15;
        ob[idx] = s_xt[l*SX + c] + s_f[l*SF + c];
    }
}

extern "C" void kernel_launch(void* const* d_in, const int* in_sizes, int n_in,
                              void* d_out, int out_size, void* d_ws, size_t ws_size,
                              hipStream_t stream)
{
    const float* x      = (const float*)d_in[0];
    const float* c11_w  = (const float*)d_in[1];
    const float* c11_b  = (const float*)d_in[2];
    const float* c12_w  = (const float*)d_in[3];
    const float* c12_b  = (const float*)d_in[4];
    const float* lse1_w = (const float*)d_in[5];
    const float* lse1_b = (const float*)d_in[6];
    const float* lse2_w = (const float*)d_in[7];
    const float* lse2_b = (const float*)d_in[8];
    const float* ln1_g  = (const float*)d_in[9];
    const float* ln1_b  = (const float*)d_in[10];
    const float* ln2_g  = (const float*)d_in[11];
    const float* ln2_b  = (const float*)d_in[12];
    const float* mlp1_w = (const float*)d_in[13];
    const float* mlp1_b = (const float*)d_in[14];
    const float* mlp2_w = (const float*)d_in[15];
    const float* mlp2_b = (const float*)d_in[16];
    const float* aln_g  = (const float*)d_in[17];
    const float* aln_b  = (const float*)d_in[18];
    const float* qkv_w  = (const float*)d_in[19];
    const float* qkv_b  = (const float*)d_in[20];
    const float* proj_w = (const float*)d_in[21];
    const float* proj_b = (const float*)d_in[22];
    const float* relpos = (const float*)d_in[23];
    const float* fln_g  = (const float*)d_in[24];
    const float* fln_b  = (const float*)d_in[25];
    const float* ff1_w  = (const float*)d_in[26];
    const float* ff1_b  = (const float*)d_in[27];
    const float* ff2_w  = (const float*)d_in[28];
    const float* ff2_b  = (const float*)d_in[29];

    const int B = in_sizes[0] / (128 * 16);

    vse_fused<<<dim3(B), dim3(256), 0, stream>>>(
        x, c11_w, c11_b, c12_w, c12_b, lse1_w, lse1_b, lse2_w, lse2_b,
        ln1_g, ln1_b, ln2_g, ln2_b, mlp1_w, mlp1_b, mlp2_w, mlp2_b,
        aln_g, aln_b, qkv_w, qkv_b, proj_w, proj_b, relpos,
        fln_g, fln_b, ff1_w, ff1_b, ff2_w, ff2_b,
        (float*)d_out);
}

// Round 4
// 1568.289 us; speedup vs baseline: 1.0189x; 1.0189x over previous
//
#include <hip/hip_runtime.h>
#include <math.h>

#define SA 68    // stride (floats) for [16][64] buffers
#define SX 132   // stride for [16][128] buffers

__device__ __forceinline__ float lrelu_f(float v){ return v > 0.f ? v : 0.01f*v; }
__device__ __forceinline__ float gelu_f(float v){ return 0.5f*v*(1.f + erff(v*0.70710678118654752f)); }

// out[l][d] (d over ND*64 cols) = act( in[l][:] @ W[d][:]^T + bias ), optional +=
// l = tid&15 (16 rows), dq = tid>>4 (16 col-quads). All strides/trip counts compile-time.
template<int ND, int K, int WS, int IS, int OS>
__device__ __forceinline__ void gemm_nd(const float* __restrict__ in,
                                        const float* __restrict__ W,
                                        const float* __restrict__ bias,
                                        float* __restrict__ outp,
                                        int tid, int act, bool accum)
{
    const int l  = tid & 15;
    const int dq = tid >> 4;
    float acc[ND][4];
#pragma unroll
    for (int nb = 0; nb < ND; ++nb)
#pragma unroll
        for (int dd = 0; dd < 4; ++dd) acc[nb][dd] = 0.f;
    const float* inrow = in + l*IS;
    const float* wbase = W + (size_t)dq*4*WS;
#pragma unroll 8
    for (int k = 0; k < K; k += 4) {
        const float4 a4 = *(const float4*)(inrow + k);
#pragma unroll
        for (int nb = 0; nb < ND; ++nb) {
#pragma unroll
            for (int dd = 0; dd < 4; ++dd) {
                const float4 w4 = *(const float4*)(wbase + (size_t)(nb*64 + dd)*WS + k);
                acc[nb][dd] += w4.x*a4.x + w4.y*a4.y + w4.z*a4.z + w4.w*a4.w;
            }
        }
    }
#pragma unroll
    for (int nb = 0; nb < ND; ++nb)
#pragma unroll
        for (int dd = 0; dd < 4; ++dd) {
            const int d = nb*64 + dq*4 + dd;
            float v = acc[nb][dd] + (bias ? bias[d] : 0.f);
            if (act == 1) v = v > 0.f ? v : 0.f;      // relu
            else if (act == 2) v = gelu_f(v);         // gelu
            float* o = outp + l*OS + d;
            if (accum) *o += v; else *o = v;
        }
}

// LayerNorm over 16 rows x 64 cols (stride SA); optional roll: src row r -> dst row (r+8)&15
__device__ __forceinline__ void ln16x64(const float* __restrict__ in,
                                        float* __restrict__ outb,
                                        const float* __restrict__ g, const float* __restrict__ bvec,
                                        int tid, bool roll)
{
    const int r = tid >> 4, c0 = (tid & 15) * 4;
    const float4 v = *(const float4*)(in + r*SA + c0);
    float s  = v.x + v.y + v.z + v.w;
    float sq = v.x*v.x + v.y*v.y + v.z*v.z + v.w*v.w;
#pragma unroll
    for (int m = 1; m < 16; m <<= 1) { s += __shfl_xor(s, m, 64); sq += __shfl_xor(sq, m, 64); }
    const float mean = s * (1.f/64.f);
    const float var  = sq * (1.f/64.f) - mean*mean;
    const float rstd = rsqrtf(var + 1e-5f);
    const int rd = roll ? ((r + 8) & 15) : r;
    const float4 gv = *(const float4*)(g + c0);
    const float4 bv = *(const float4*)(bvec + c0);
    float4 o;
    o.x = (v.x-mean)*rstd*gv.x + bv.x;
    o.y = (v.y-mean)*rstd*gv.y + bv.y;
    o.z = (v.z-mean)*rstd*gv.z + bv.z;
    o.w = (v.w-mean)*rstd*gv.w + bv.w;
    *(float4*)(outb + rd*SA + c0) = o;
}

// width-3 conv over L=16, zero pad, leaky-relu. layouts [ch][16].
// mode 0: outb = lrelu(conv(in)); mode 1: cxbuf = lrelu(conv(in)) + 2*cxbuf
__device__ __forceinline__ void conv3_lrelu(const float* __restrict__ in,
                                            float* __restrict__ outb,
                                            const float* __restrict__ w, const float* __restrict__ bias,
                                            int tid, int mode, float* __restrict__ cxbuf)
{
    const int o = tid >> 2, l0 = (tid & 3) * 4;
    float acc[4] = {0.f, 0.f, 0.f, 0.f};
    const float* wr0 = w + (size_t)o*64*3;
#pragma unroll 8
    for (int i = 0; i < 64; ++i) {
        const float* wr = wr0 + i*3;
        const float w0 = wr[0], w1 = wr[1], w2 = wr[2];
        const float* row = in + i*16 + l0;
        const float xm1 = (l0 == 0)  ? 0.f : row[-1];
        const float x0 = row[0], x1 = row[1], x2 = row[2], x3 = row[3];
        const float xp1 = (l0 == 12) ? 0.f : row[4];
        acc[0] += w0*xm1 + w1*x0 + w2*x1;
        acc[1] += w0*x0  + w1*x1 + w2*x2;
        acc[2] += w0*x1  + w1*x2 + w2*x3;
        acc[3] += w0*x2  + w1*x3 + w2*xp1;
    }
    const float bb = bias[o];
    if (mode == 0) {
#pragma unroll
        for (int j = 0; j < 4; ++j) outb[o*16 + l0 + j] = lrelu_f(acc[j] + bb);
    } else {
#pragma unroll
        for (int j = 0; j < 4; ++j) {
            float* p = cxbuf + o*16 + l0 + j;
            *p = lrelu_f(acc[j] + bb) + 2.f * (*p);
        }
    }
}

__global__ __launch_bounds__(256, 4) void vse_fused(
    const float* __restrict__ x,
    const float* __restrict__ c11_w, const float* __restrict__ c11_b,
    const float* __restrict__ c12_w, const float* __restrict__ c12_b,
    const float* __restrict__ lse1_w, const float* __restrict__ lse1_b,
    const float* __restrict__ lse2_w, const float* __restrict__ lse2_b,
    const float* __restrict__ ln1_g, const float* __restrict__ ln1_b,
    const float* __restrict__ ln2_g, const float* __restrict__ ln2_b,
    const float* __restrict__ mlp1_w, const float* __restrict__ mlp1_b,
    const float* __restrict__ mlp2_w, const float* __restrict__ mlp2_b,
    const float* __restrict__ aln_g, const float* __restrict__ aln_b,
    const float* __restrict__ qkv_w, const float* __restrict__ qkv_b,
    const float* __restrict__ proj_w, const float* __restrict__ proj_b,
    const float* __restrict__ relpos,
    const float* __restrict__ fln_g, const float* __restrict__ fln_b,
    const float* __restrict__ ff1_w, const float* __restrict__ ff1_b,
    const float* __restrict__ ff2_w, const float* __restrict__ ff2_b,
    float* __restrict__ out)
{
    // ---- phase-aliased LDS pool: 9664 floats = 38656 B -> 4 blocks/CU ----
    __shared__ float pool[9664];
    float* const s_h   = pool;            // 1088  residual h (live whole kernel)
    float* const s_z   = pool + 1088;     // 1088  transformer stream
    float* const s_a   = pool + 2176;     // 1088  LN out  (phase-alias: conv temp)
    float* const s_q   = pool + 3264;     // 1088  (phase-alias: x^T [0:2112], concat)
    float* const s_k   = pool + 4352;     // 1088
    float* const s_v   = pool + 5440;     // 1088
    float* const s_fh  = pool + 6528;     // 2112  ff-half / c11-out / attn-o+att / res
    float* const s_cx  = pool + 8640;     // 1024  conv branch [c][l] (live whole kernel)
    float* const s_xt  = s_q;             // phase 0: x^T [16][SX] (2112 <= q+k = 2176)
    float* const s_y   = s_fh;            // phase 0: c11 out [16][SX]
    float* const s_t1  = s_a;             // conv temp [64][16] (1024 <= 1088)
    float* const s_o   = s_fh;            // attn out [16][SA]
    float* const s_att = s_fh + 1088;     // attn probs [16][16]
    float* const s_cat = s_q;             // final concat [16][SX]
    float* const s_res = s_fh;            // final res [16][SX]

    const int tid = threadIdx.x;
    const int b = blockIdx.x;
    const float* xb = x + (size_t)b * 2048;

    // ---- load x transposed ----
#pragma unroll
    for (int it = 0; it < 8; ++it) {
        const int idx = tid + it*256;           // = c*16 + l
        const int c = idx >> 4, l = idx & 15;
        s_xt[l*SX + c] = xb[idx];
    }
    __syncthreads();

    // ---- c11 (1x1 conv = 128x128 matmul) + relu ----
    gemm_nd<2,128,128,SX,SX>(s_xt, c11_w, c11_b, s_y, tid, 1, false);
    __syncthreads();

    // ---- split: conv_x [c][l], h [l][d] ----
#pragma unroll
    for (int it = 0; it < 4; ++it) {
        const int idx = tid + it*256;           // 0..1023
        const int i = idx & 63, l = idx >> 6;
        s_cx[i*16 + l] = s_y[l*SX + i];
        s_h [l*SA + i] = s_y[l*SX + 64 + i];
    }
    __syncthreads();

    // ---- conv branch ----
    conv3_lrelu(s_cx, s_t1, lse1_w, lse1_b, tid, 0, nullptr);
    __syncthreads();
    conv3_lrelu(s_t1, nullptr, lse2_w, lse2_b, tid, 1, s_cx);
    __syncthreads();

    // ---- z = LN(h, ln1) ----
    ln16x64(s_h, s_z, ln1_g, ln1_b, tid, false);
    __syncthreads();

    // ---- transformer layers ----
    for (int layer = 0; layer < 2; ++layer) {
        const float* qkv_wl  = qkv_w + (size_t)layer * 1536 * 64;
        const float* qkv_bl  = qkv_b + layer * 1536;
        const float* proj_wl = proj_w + (size_t)layer * 64 * 512;
        const float* proj_bl = proj_b + layer * 64;
        const float* rel_l   = relpos + layer * 8 * 49;

        // a = roll(LN(z, aln), -8)
        ln16x64(s_z, s_a, aln_g + layer*64, aln_b + layer*64, tid, true);
        __syncthreads();

        for (int hh = 0; hh < 8; ++hh) {
            gemm_nd<1,64,64,SA,SA>(s_a, qkv_wl + (size_t)(hh*64)*64,        qkv_bl + hh*64,        s_q, tid, 0, false);
            gemm_nd<1,64,64,SA,SA>(s_a, qkv_wl + (size_t)(512 + hh*64)*64,  qkv_bl + 512 + hh*64,  s_k, tid, 0, false);
            gemm_nd<1,64,64,SA,SA>(s_a, qkv_wl + (size_t)(1024 + hh*64)*64, qkv_bl + 1024 + hh*64, s_v, tid, 0, false);
            __syncthreads();

            {   // dots + relpos + mask + softmax (thread (i,j) holds one score)
                const int i = tid >> 4, j = tid & 15;
                const float* qi = s_q + i*SA;
                const float* kj = s_k + j*SA;
                float dot = 0.f;
#pragma unroll
                for (int d0 = 0; d0 < 64; d0 += 4) {
                    const float4 qv = *(const float4*)(qi + d0);
                    const float4 kv = *(const float4*)(kj + d0);
                    dot += qv.x*kv.x + qv.y*kv.y + qv.z*kv.z + qv.w*kv.w;
                }
                float val = dot * 0.125f
                          + rel_l[hh*49 + ((i>>2) - (j>>2) + 3)*7 + ((i&3) - (j&3) + 3)];
                const bool masked = ((hh >= 6) && (((i>>2) < 2) != ((j>>2) < 2)))
                                 || ((hh & 1) && (((i&3) < 2) != ((j&3) < 2)));
                if (masked) val = -1e9f;
                float mx = val;
#pragma unroll
                for (int m = 1; m < 16; m <<= 1) mx = fmaxf(mx, __shfl_xor(mx, m, 64));
                const float e = expf(val - mx);
                float ssum = e;
#pragma unroll
                for (int m = 1; m < 16; m <<= 1) ssum += __shfl_xor(ssum, m, 64);
                s_att[i*16 + j] = e / ssum;
            }
            __syncthreads();

            {   // out_h = attn @ v
                const int l = tid & 15, dq = tid >> 4;
                float a0 = 0.f, a1 = 0.f, a2 = 0.f, a3 = 0.f;
#pragma unroll
                for (int j = 0; j < 16; ++j) {
                    const float at = s_att[l*16 + j];
                    const float4 v4 = *(const float4*)(s_v + j*SA + dq*4);
                    a0 += at*v4.x; a1 += at*v4.y; a2 += at*v4.z; a3 += at*v4.w;
                }
                float* op = s_o + l*SA + dq*4;
                op[0] = a0; op[1] = a1; op[2] = a2; op[3] = a3;
            }
            __syncthreads();

            // z += o @ proj_slice^T (bias on first head only)
            gemm_nd<1,64,512,SA,SA>(s_o, proj_wl + hh*64,
                                    (hh == 0) ? proj_bl : nullptr, s_z, tid, 0, true);
            __syncthreads();
        }

        // FF block: two 128-col passes through s_fh
        ln16x64(s_z, s_a, fln_g + layer*64, fln_b + layer*64, tid, false);
        __syncthreads();
#pragma unroll
        for (int p = 0; p < 2; ++p) {
            gemm_nd<2,64,64,SA,SX>(s_a, ff1_w + (size_t)layer*256*64 + (size_t)p*128*64,
                                   ff1_b + layer*256 + p*128, s_fh, tid, 2, false);
            __syncthreads();
            gemm_nd<1,128,256,SX,SA>(s_fh, ff2_w + (size_t)layer*64*256 + p*128,
                                     (p == 0) ? (ff2_b + layer*64) : nullptr, s_z, tid, 0, true);
            __syncthreads();
        }
    }

    // ---- h += z; mlp block on h (two 128-col passes) ----
#pragma unroll
    for (int it = 0; it < 4; ++it) {
        const int idx = tid + it*256;
        const int d = idx & 63, l = idx >> 6;
        s_h[l*SA + d] += s_z[l*SA + d];
    }
    __syncthreads();
    ln16x64(s_h, s_a, ln2_g, ln2_b, tid, false);
    __syncthreads();
#pragma unroll
    for (int p = 0; p < 2; ++p) {
        gemm_nd<2,64,64,SA,SX>(s_a, mlp1_w + (size_t)p*128*64, mlp1_b + p*128, s_fh, tid, 2, false);
        __syncthreads();
        gemm_nd<1,128,256,SX,SA>(s_fh, mlp2_w + p*128,
                                 (p == 0) ? mlp2_b : nullptr, s_h, tid, 0, true);
        __syncthreads();
    }

    // ---- concat [conv_x ; h^T] into s_cat [l][i] ----
#pragma unroll
    for (int it = 0; it < 8; ++it) {
        const int idx = tid + it*256;           // 0..2047
        const int i = idx & 127, l = idx >> 7;
        s_cat[l*SX + i] = (i < 64) ? s_cx[i*16 + l] : s_h[l*SA + (i - 64)];
    }
    __syncthreads();

    // ---- c12 (1x1 conv) -> s_res [l][c] ----
    gemm_nd<2,128,128,SX,SX>(s_cat, c12_w, c12_b, s_res, tid, 0, false);
    __syncthreads();

    // ---- out = x + res (x reloaded from global) ----
    float* ob = out + (size_t)b * 2048;
#pragma unroll
    for (int it = 0; it < 8; ++it) {
        const int idx = tid + it*256;           // = c*16 + l
        const int c = idx >> 4, l = idx & 15;
        ob[idx] = xb[idx] + s_res[l*SX + c];
    }
}

extern "C" void kernel_launch(void* const* d_in, const int* in_sizes, int n_in,
                              void* d_out, int out_size, void* d_ws, size_t ws_size,
                              hipStream_t stream)
{
    const float* x      = (const float*)d_in[0];
    const float* c11_w  = (const float*)d_in[1];
    const float* c11_b  = (const float*)d_in[2];
    const float* c12_w  = (const float*)d_in[3];
    const float* c12_b  = (const float*)d_in[4];
    const float* lse1_w = (const float*)d_in[5];
    const float* lse1_b = (const float*)d_in[6];
    const float* lse2_w = (const float*)d_in[7];
    const float* lse2_b = (const float*)d_in[8];
    const float* ln1_g  = (const float*)d_in[9];
    const float* ln1_b  = (const float*)d_in[10];
    const float* ln2_g  = (const float*)d_in[11];
    const float* ln2_b  = (const float*)d_in[12];
    const float* mlp1_w = (const float*)d_in[13];
    const float* mlp1_b = (const float*)d_in[14];
    const float* mlp2_w = (const float*)d_in[15];
    const float* mlp2_b = (const float*)d_in[16];
    const float* aln_g  = (const float*)d_in[17];
    const float* aln_b  = (const float*)d_in[18];
    const float* qkv_w  = (const float*)d_in[19];
    const float* qkv_b  = (const float*)d_in[20];
    const float* proj_w = (const float*)d_in[21];
    const float* proj_b = (const float*)d_in[22];
    const float* relpos = (const float*)d_in[23];
    const float* fln_g  = (const float*)d_in[24];
    const float* fln_b  = (const float*)d_in[25];
    const float* ff1_w  = (const float*)d_in[26];
    const float* ff1_b  = (const float*)d_in[27];
    const float* ff2_w  = (const float*)d_in[28];
    const float* ff2_b  = (const float*)d_in[29];

    const int B = in_sizes[0] / (128 * 16);

    vse_fused<<<dim3(B), dim3(256), 0, stream>>>(
        x, c11_w, c11_b, c12_w, c12_b, lse1_w, lse1_b, lse2_w, lse2_b,
        ln1_g, ln1_b, ln2_g, ln2_b, mlp1_w, mlp1_b, mlp2_w, mlp2_b,
        aln_g, aln_b, qkv_w, qkv_b, proj_w, proj_b, relpos,
        fln_g, fln_b, ff1_w, ff1_b, ff2_w, ff2_b,
        (float*)d_out);
}

// Round 5
// 1546.341 us; speedup vs baseline: 1.0333x; 1.0142x over previous
//
#include <hip/hip_runtime.h>
#include <math.h>

#define SA 68    // stride (floats) for [16][64] buffers
#define SX 132   // stride for [16][128] buffers

__device__ __forceinline__ float lrelu_f(float v){ return v > 0.f ? v : 0.01f*v; }
__device__ __forceinline__ float gelu_f(float v){ return 0.5f*v*(1.f + erff(v*0.70710678118654752f)); }

// out[l][d] (d over ND*64 cols) = act( in[l][:] @ W[d][:]^T + bias ), optional +=
// l = tid&15 (16 rows), dq = tid>>4 (16 col-quads). All strides/trip counts compile-time.
template<int ND, int K, int WS, int IS, int OS>
__device__ __forceinline__ void gemm_nd(const float* __restrict__ in,
                                        const float* __restrict__ W,
                                        const float* __restrict__ bias,
                                        float* __restrict__ outp,
                                        int tid, int act, bool accum)
{
    const int l  = tid & 15;
    const int dq = tid >> 4;
    float acc[ND][4];
#pragma unroll
    for (int nb = 0; nb < ND; ++nb)
#pragma unroll
        for (int dd = 0; dd < 4; ++dd) acc[nb][dd] = 0.f;
    const float* inrow = in + l*IS;
    const float* wbase = W + (size_t)dq*4*WS;
#pragma unroll 4
    for (int k = 0; k < K; k += 4) {
        const float4 a4 = *(const float4*)(inrow + k);
#pragma unroll
        for (int nb = 0; nb < ND; ++nb) {
#pragma unroll
            for (int dd = 0; dd < 4; ++dd) {
                const float4 w4 = *(const float4*)(wbase + (size_t)(nb*64 + dd)*WS + k);
                acc[nb][dd] += w4.x*a4.x + w4.y*a4.y + w4.z*a4.z + w4.w*a4.w;
            }
        }
    }
#pragma unroll
    for (int nb = 0; nb < ND; ++nb)
#pragma unroll
        for (int dd = 0; dd < 4; ++dd) {
            const int d = nb*64 + dq*4 + dd;
            float v = acc[nb][dd] + (bias ? bias[d] : 0.f);
            if (act == 1) v = v > 0.f ? v : 0.f;      // relu
            else if (act == 2) v = gelu_f(v);         // gelu
            float* o = outp + l*OS + d;
            if (accum) *o += v; else *o = v;
        }
}

// LayerNorm over 16 rows x 64 cols (stride SA); optional roll: src row r -> dst row (r+8)&15
__device__ __forceinline__ void ln16x64(const float* __restrict__ in,
                                        float* __restrict__ outb,
                                        const float* __restrict__ g, const float* __restrict__ bvec,
                                        int tid, bool roll)
{
    const int r = tid >> 4, c0 = (tid & 15) * 4;
    const float4 v = *(const float4*)(in + r*SA + c0);
    float s  = v.x + v.y + v.z + v.w;
    float sq = v.x*v.x + v.y*v.y + v.z*v.z + v.w*v.w;
#pragma unroll
    for (int m = 1; m < 16; m <<= 1) { s += __shfl_xor(s, m, 64); sq += __shfl_xor(sq, m, 64); }
    const float mean = s * (1.f/64.f);
    const float var  = sq * (1.f/64.f) - mean*mean;
    const float rstd = rsqrtf(var + 1e-5f);
    const int rd = roll ? ((r + 8) & 15) : r;
    const float4 gv = *(const float4*)(g + c0);
    const float4 bv = *(const float4*)(bvec + c0);
    float4 o;
    o.x = (v.x-mean)*rstd*gv.x + bv.x;
    o.y = (v.y-mean)*rstd*gv.y + bv.y;
    o.z = (v.z-mean)*rstd*gv.z + bv.z;
    o.w = (v.w-mean)*rstd*gv.w + bv.w;
    *(float4*)(outb + rd*SA + c0) = o;
}

// width-3 conv over L=16, zero pad, leaky-relu. layouts [ch][16].
// mode 0: outb = lrelu(conv(in)); mode 1: cxbuf = lrelu(conv(in)) + 2*cxbuf
__device__ __forceinline__ void conv3_lrelu(const float* __restrict__ in,
                                            float* __restrict__ outb,
                                            const float* __restrict__ w, const float* __restrict__ bias,
                                            int tid, int mode, float* __restrict__ cxbuf)
{
    const int o = tid >> 2, l0 = (tid & 3) * 4;
    float acc[4] = {0.f, 0.f, 0.f, 0.f};
    const float* wr0 = w + (size_t)o*64*3;
#pragma unroll 4
    for (int i = 0; i < 64; ++i) {
        const float* wr = wr0 + i*3;
        const float w0 = wr[0], w1 = wr[1], w2 = wr[2];
        const float* row = in + i*16 + l0;
        const float xm1 = (l0 == 0)  ? 0.f : row[-1];
        const float x0 = row[0], x1 = row[1], x2 = row[2], x3 = row[3];
        const float xp1 = (l0 == 12) ? 0.f : row[4];
        acc[0] += w0*xm1 + w1*x0 + w2*x1;
        acc[1] += w0*x0  + w1*x1 + w2*x2;
        acc[2] += w0*x1  + w1*x2 + w2*x3;
        acc[3] += w0*x2  + w1*x3 + w2*xp1;
    }
    const float bb = bias[o];
    if (mode == 0) {
#pragma unroll
        for (int j = 0; j < 4; ++j) outb[o*16 + l0 + j] = lrelu_f(acc[j] + bb);
    } else {
#pragma unroll
        for (int j = 0; j < 4; ++j) {
            float* p = cxbuf + o*16 + l0 + j;
            *p = lrelu_f(acc[j] + bb) + 2.f * (*p);
        }
    }
}

__global__ __launch_bounds__(256, 2) void vse_fused(
    const float* __restrict__ x,
    const float* __restrict__ c11_w, const float* __restrict__ c11_b,
    const float* __restrict__ c12_w, const float* __restrict__ c12_b,
    const float* __restrict__ lse1_w, const float* __restrict__ lse1_b,
    const float* __restrict__ lse2_w, const float* __restrict__ lse2_b,
    const float* __restrict__ ln1_g, const float* __restrict__ ln1_b,
    const float* __restrict__ ln2_g, const float* __restrict__ ln2_b,
    const float* __restrict__ mlp1_w, const float* __restrict__ mlp1_b,
    const float* __restrict__ mlp2_w, const float* __restrict__ mlp2_b,
    const float* __restrict__ aln_g, const float* __restrict__ aln_b,
    const float* __restrict__ qkv_w, const float* __restrict__ qkv_b,
    const float* __restrict__ proj_w, const float* __restrict__ proj_b,
    const float* __restrict__ relpos,
    const float* __restrict__ fln_g, const float* __restrict__ fln_b,
    const float* __restrict__ ff1_w, const float* __restrict__ ff1_b,
    const float* __restrict__ ff2_w, const float* __restrict__ ff2_b,
    float* __restrict__ out)
{
    // ---- phase-aliased LDS pool: 9664 floats = 38656 B -> 4 blocks/CU ----
    __shared__ float pool[9664];
    float* const s_h   = pool;            // 1088  residual h (live whole kernel)
    float* const s_z   = pool + 1088;     // 1088  transformer stream
    float* const s_a   = pool + 2176;     // 1088  LN out  (phase-alias: conv temp)
    float* const s_q   = pool + 3264;     // 1088  (phase-alias: x^T [0:2112], concat)
    float* const s_k   = pool + 4352;     // 1088
    float* const s_v   = pool + 5440;     // 1088
    float* const s_fh  = pool + 6528;     // 2112  ff-half / c11-out / attn-o+att / res
    float* const s_cx  = pool + 8640;     // 1024  conv branch [c][l] (live whole kernel)
    float* const s_xt  = s_q;             // phase 0: x^T [16][SX] (2112 <= q+k = 2176)
    float* const s_y   = s_fh;            // phase 0: c11 out [16][SX]
    float* const s_t1  = s_a;             // conv temp [64][16] (1024 <= 1088)
    float* const s_o   = s_fh;            // attn out [16][SA]
    float* const s_att = s_fh + 1088;     // attn probs [16][16]
    float* const s_cat = s_q;             // final concat [16][SX]
    float* const s_res = s_fh;            // final res [16][SX]

    const int tid = threadIdx.x;
    const int b = blockIdx.x;
    const float* xb = x + (size_t)b * 2048;

    // ---- load x transposed ----
#pragma unroll
    for (int it = 0; it < 8; ++it) {
        const int idx = tid + it*256;           // = c*16 + l
        const int c = idx >> 4, l = idx & 15;
        s_xt[l*SX + c] = xb[idx];
    }
    __syncthreads();

    // ---- c11 (1x1 conv = 128x128 matmul) + relu ----
    gemm_nd<2,128,128,SX,SX>(s_xt, c11_w, c11_b, s_y, tid, 1, false);
    __syncthreads();

    // ---- split: conv_x [c][l], h [l][d] ----
#pragma unroll
    for (int it = 0; it < 4; ++it) {
        const int idx = tid + it*256;           // 0..1023
        const int i = idx & 63, l = idx >> 6;
        s_cx[i*16 + l] = s_y[l*SX + i];
        s_h [l*SA + i] = s_y[l*SX + 64 + i];
    }
    __syncthreads();

    // ---- conv branch ----
    conv3_lrelu(s_cx, s_t1, lse1_w, lse1_b, tid, 0, nullptr);
    __syncthreads();
    conv3_lrelu(s_t1, nullptr, lse2_w, lse2_b, tid, 1, s_cx);
    __syncthreads();

    // ---- z = LN(h, ln1) ----
    ln16x64(s_h, s_z, ln1_g, ln1_b, tid, false);
    __syncthreads();

    // ---- transformer layers ----
    for (int layer = 0; layer < 2; ++layer) {
        const float* qkv_wl  = qkv_w + (size_t)layer * 1536 * 64;
        const float* qkv_bl  = qkv_b + layer * 1536;
        const float* proj_wl = proj_w + (size_t)layer * 64 * 512;
        const float* proj_bl = proj_b + layer * 64;
        const float* rel_l   = relpos + layer * 8 * 49;

        // a = roll(LN(z, aln), -8)
        ln16x64(s_z, s_a, aln_g + layer*64, aln_b + layer*64, tid, true);
        __syncthreads();

        for (int hh = 0; hh < 8; ++hh) {
            gemm_nd<1,64,64,SA,SA>(s_a, qkv_wl + (size_t)(hh*64)*64,        qkv_bl + hh*64,        s_q, tid, 0, false);
            gemm_nd<1,64,64,SA,SA>(s_a, qkv_wl + (size_t)(512 + hh*64)*64,  qkv_bl + 512 + hh*64,  s_k, tid, 0, false);
            gemm_nd<1,64,64,SA,SA>(s_a, qkv_wl + (size_t)(1024 + hh*64)*64, qkv_bl + 1024 + hh*64, s_v, tid, 0, false);
            __syncthreads();

            {   // dots + relpos + mask + softmax (thread (i,j) holds one score)
                const int i = tid >> 4, j = tid & 15;
                const float* qi = s_q + i*SA;
                const float* kj = s_k + j*SA;
                float dot = 0.f;
#pragma unroll
                for (int d0 = 0; d0 < 64; d0 += 4) {
                    const float4 qv = *(const float4*)(qi + d0);
                    const float4 kv = *(const float4*)(kj + d0);
                    dot += qv.x*kv.x + qv.y*kv.y + qv.z*kv.z + qv.w*kv.w;
                }
                float val = dot * 0.125f
                          + rel_l[hh*49 + ((i>>2) - (j>>2) + 3)*7 + ((i&3) - (j&3) + 3)];
                const bool masked = ((hh >= 6) && (((i>>2) < 2) != ((j>>2) < 2)))
                                 || ((hh & 1) && (((i&3) < 2) != ((j&3) < 2)));
                if (masked) val = -1e9f;
                float mx = val;
#pragma unroll
                for (int m = 1; m < 16; m <<= 1) mx = fmaxf(mx, __shfl_xor(mx, m, 64));
                const float e = expf(val - mx);
                float ssum = e;
#pragma unroll
                for (int m = 1; m < 16; m <<= 1) ssum += __shfl_xor(ssum, m, 64);
                s_att[i*16 + j] = e / ssum;
            }
            __syncthreads();

            {   // out_h = attn @ v
                const int l = tid & 15, dq = tid >> 4;
                float a0 = 0.f, a1 = 0.f, a2 = 0.f, a3 = 0.f;
#pragma unroll
                for (int j = 0; j < 16; ++j) {
                    const float at = s_att[l*16 + j];
                    const float4 v4 = *(const float4*)(s_v + j*SA + dq*4);
                    a0 += at*v4.x; a1 += at*v4.y; a2 += at*v4.z; a3 += at*v4.w;
                }
                float* op = s_o + l*SA + dq*4;
                op[0] = a0; op[1] = a1; op[2] = a2; op[3] = a3;
            }
            __syncthreads();

            // z += o @ proj_slice^T (bias on first head only)
            gemm_nd<1,64,512,SA,SA>(s_o, proj_wl + hh*64,
                                    (hh == 0) ? proj_bl : nullptr, s_z, tid, 0, true);
            __syncthreads();
        }

        // FF block: two 128-col passes through s_fh
        ln16x64(s_z, s_a, fln_g + layer*64, fln_b + layer*64, tid, false);
        __syncthreads();
#pragma unroll
        for (int p = 0; p < 2; ++p) {
            gemm_nd<2,64,64,SA,SX>(s_a, ff1_w + (size_t)layer*256*64 + (size_t)p*128*64,
                                   ff1_b + layer*256 + p*128, s_fh, tid, 2, false);
            __syncthreads();
            gemm_nd<1,128,256,SX,SA>(s_fh, ff2_w + (size_t)layer*64*256 + p*128,
                                     (p == 0) ? (ff2_b + layer*64) : nullptr, s_z, tid, 0, true);
            __syncthreads();
        }
    }

    // ---- h += z; mlp block on h (two 128-col passes) ----
#pragma unroll
    for (int it = 0; it < 4; ++it) {
        const int idx = tid + it*256;
        const int d = idx & 63, l = idx >> 6;
        s_h[l*SA + d] += s_z[l*SA + d];
    }
    __syncthreads();
    ln16x64(s_h, s_a, ln2_g, ln2_b, tid, false);
    __syncthreads();
#pragma unroll
    for (int p = 0; p < 2; ++p) {
        gemm_nd<2,64,64,SA,SX>(s_a, mlp1_w + (size_t)p*128*64, mlp1_b + p*128, s_fh, tid, 2, false);
        __syncthreads();
        gemm_nd<1,128,256,SX,SA>(s_fh, mlp2_w + p*128,
                                 (p == 0) ? mlp2_b : nullptr, s_h, tid, 0, true);
        __syncthreads();
    }

    // ---- concat [conv_x ; h^T] into s_cat [l][i] ----
#pragma unroll
    for (int it = 0; it < 8; ++it) {
        const int idx = tid + it*256;           // 0..2047
        const int i = idx & 127, l = idx >> 7;
        s_cat[l*SX + i] = (i < 64) ? s_cx[i*16 + l] : s_h[l*SA + (i - 64)];
    }
    __syncthreads();

    // ---- c12 (1x1 conv) -> s_res [l][c] ----
    gemm_nd<2,128,128,SX,SX>(s_cat, c12_w, c12_b, s_res, tid, 0, false);
    __syncthreads();

    // ---- out = x + res (x reloaded from global) ----
    float* ob = out + (size_t)b * 2048;
#pragma unroll
    for (int it = 0; it < 8; ++it) {
        const int idx = tid + it*256;           // = c*16 + l
        const int c = idx >> 4, l = idx & 15;
        ob[idx] = xb[idx] + s_res[l*SX + c];
    }
}

extern "C" void kernel_launch(void* const* d_in, const int* in_sizes, int n_in,
                              void* d_out, int out_size, void* d_ws, size_t ws_size,
                              hipStream_t stream)
{
    const float* x      = (const float*)d_in[0];
    const float* c11_w  = (const float*)d_in[1];
    const float* c11_b  = (const float*)d_in[2];
    const float* c12_w  = (const float*)d_in[3];
    const float* c12_b  = (const float*)d_in[4];
    const float* lse1_w = (const float*)d_in[5];
    const float* lse1_b = (const float*)d_in[6];
    const float* lse2_w = (const float*)d_in[7];
    const float* lse2_b = (const float*)d_in[8];
    const float* ln1_g  = (const float*)d_in[9];
    const float* ln1_b  = (const float*)d_in[10];
    const float* ln2_g  = (const float*)d_in[11];
    const float* ln2_b  = (const float*)d_in[12];
    const float* mlp1_w = (const float*)d_in[13];
    const float* mlp1_b = (const float*)d_in[14];
    const float* mlp2_w = (const float*)d_in[15];
    const float* mlp2_b = (const float*)d_in[16];
    const float* aln_g  = (const float*)d_in[17];
    const float* aln_b  = (const float*)d_in[18];
    const float* qkv_w  = (const float*)d_in[19];
    const float* qkv_b  = (const float*)d_in[20];
    const float* proj_w = (const float*)d_in[21];
    const float* proj_b = (const float*)d_in[22];
    const float* relpos = (const float*)d_in[23];
    const float* fln_g  = (const float*)d_in[24];
    const float* fln_b  = (const float*)d_in[25];
    const float* ff1_w  = (const float*)d_in[26];
    const float* ff1_b  = (const float*)d_in[27];
    const float* ff2_w  = (const float*)d_in[28];
    const float* ff2_b  = (const float*)d_in[29];

    const int B = in_sizes[0] / (128 * 16);

    vse_fused<<<dim3(B), dim3(256), 0, stream>>>(
        x, c11_w, c11_b, c12_w, c12_b, lse1_w, lse1_b, lse2_w, lse2_b,
        ln1_g, ln1_b, ln2_g, ln2_b, mlp1_w, mlp1_b, mlp2_w, mlp2_b,
        aln_g, aln_b, qkv_w, qkv_b, proj_w, proj_b, relpos,
        fln_g, fln_b, ff1_w, ff1_b, ff2_w, ff2_b,
        (float*)d_out);
}

// Round 7
// 1477.271 us; speedup vs baseline: 1.0816x; 1.0468x over previous
//
#include <hip/hip_runtime.h>
#include <math.h>

#define SA 68    // stride (floats) for [16][64] buffers
#define SX 132   // stride for [16][128] buffers

__device__ __forceinline__ float lrelu_f(float v){ return v > 0.f ? v : 0.01f*v; }
__device__ __forceinline__ float gelu_f(float v){ return 0.5f*v*(1.f + erff(v*0.70710678118654752f)); }

// out[l][d] (d over ND*64 cols) = act( in[l][:] @ W[d][:]^T + bias ), optional +=
// l = tid&15 (16 rows), dq = tid>>4 (16 col-quads). All strides/trip counts compile-time.
// UNR = inner k-unroll factor; chosen so in-flight float4 weight loads ~= 16 (64 VGPR).
template<int ND, int K, int WS, int IS, int OS, int UNR>
__device__ __forceinline__ void gemm_nd(const float* __restrict__ in,
                                        const float* __restrict__ W,
                                        const float* __restrict__ bias,
                                        float* __restrict__ outp,
                                        int tid, int act, bool accum)
{
    const int l  = tid & 15;
    const int dq = tid >> 4;
    float acc[ND][4];
#pragma unroll
    for (int nb = 0; nb < ND; ++nb)
#pragma unroll
        for (int dd = 0; dd < 4; ++dd) acc[nb][dd] = 0.f;
    const float* inrow = in + l*IS;
    const float* wbase = W + (size_t)dq*4*WS;
#pragma unroll 1
    for (int k0 = 0; k0 < K; k0 += UNR*4) {
#pragma unroll
        for (int u = 0; u < UNR; ++u) {
            const int k = k0 + u*4;
            const float4 a4 = *(const float4*)(inrow + k);
#pragma unroll
            for (int nb = 0; nb < ND; ++nb) {
#pragma unroll
                for (int dd = 0; dd < 4; ++dd) {
                    const float4 w4 = *(const float4*)(wbase + (size_t)(nb*64 + dd)*WS + k);
                    acc[nb][dd] += w4.x*a4.x + w4.y*a4.y + w4.z*a4.z + w4.w*a4.w;
                }
            }
        }
    }
#pragma unroll
    for (int nb = 0; nb < ND; ++nb)
#pragma unroll
        for (int dd = 0; dd < 4; ++dd) {
            const int d = nb*64 + dq*4 + dd;
            float v = acc[nb][dd] + (bias ? bias[d] : 0.f);
            if (act == 1) v = v > 0.f ? v : 0.f;      // relu
            else if (act == 2) v = gelu_f(v);         // gelu
            float* o = outp + l*OS + d;
            if (accum) *o += v; else *o = v;
        }
}

// LayerNorm over 16 rows x 64 cols (stride SA); optional roll: src row r -> dst row (r+8)&15
__device__ __forceinline__ void ln16x64(const float* __restrict__ in,
                                        float* __restrict__ outb,
                                        const float* __restrict__ g, const float* __restrict__ bvec,
                                        int tid, bool roll)
{
    const int r = tid >> 4, c0 = (tid & 15) * 4;
    const float4 v = *(const float4*)(in + r*SA + c0);
    float s  = v.x + v.y + v.z + v.w;
    float sq = v.x*v.x + v.y*v.y + v.z*v.z + v.w*v.w;
#pragma unroll
    for (int m = 1; m < 16; m <<= 1) { s += __shfl_xor(s, m, 64); sq += __shfl_xor(sq, m, 64); }
    const float mean = s * (1.f/64.f);
    const float var  = sq * (1.f/64.f) - mean*mean;
    const float rstd = rsqrtf(var + 1e-5f);
    const int rd = roll ? ((r + 8) & 15) : r;
    const float4 gv = *(const float4*)(g + c0);
    const float4 bv = *(const float4*)(bvec + c0);
    float4 o;
    o.x = (v.x-mean)*rstd*gv.x + bv.x;
    o.y = (v.y-mean)*rstd*gv.y + bv.y;
    o.z = (v.z-mean)*rstd*gv.z + bv.z;
    o.w = (v.w-mean)*rstd*gv.w + bv.w;
    *(float4*)(outb + rd*SA + c0) = o;
}

// width-3 conv over L=16, zero pad, leaky-relu. layouts [ch][16].
// mode 0: outb = lrelu(conv(in)); mode 1: cxbuf = lrelu(conv(in)) + 2*cxbuf
__device__ __forceinline__ void conv3_lrelu(const float* __restrict__ in,
                                            float* __restrict__ outb,
                                            const float* __restrict__ w, const float* __restrict__ bias,
                                            int tid, int mode, float* __restrict__ cxbuf)
{
    const int o = tid >> 2, l0 = (tid & 3) * 4;
    float acc[4] = {0.f, 0.f, 0.f, 0.f};
    const float* wr0 = w + (size_t)o*64*3;
#pragma unroll 4
    for (int i = 0; i < 64; ++i) {
        const float* wr = wr0 + i*3;
        const float w0 = wr[0], w1 = wr[1], w2 = wr[2];
        const float* row = in + i*16 + l0;
        const float xm1 = (l0 == 0)  ? 0.f : row[-1];
        const float x0 = row[0], x1 = row[1], x2 = row[2], x3 = row[3];
        const float xp1 = (l0 == 12) ? 0.f : row[4];
        acc[0] += w0*xm1 + w1*x0 + w2*x1;
        acc[1] += w0*x0  + w1*x1 + w2*x2;
        acc[2] += w0*x1  + w1*x2 + w2*x3;
        acc[3] += w0*x2  + w1*x3 + w2*xp1;
    }
    const float bb = bias[o];
    if (mode == 0) {
#pragma unroll
        for (int j = 0; j < 4; ++j) outb[o*16 + l0 + j] = lrelu_f(acc[j] + bb);
    } else {
#pragma unroll
        for (int j = 0; j < 4; ++j) {
            float* p = cxbuf + o*16 + l0 + j;
            *p = lrelu_f(acc[j] + bb) + 2.f * (*p);
        }
    }
}

__global__ __launch_bounds__(256)
__attribute__((amdgpu_waves_per_eu(4, 4)))
void vse_fused(
    const float* __restrict__ x,
    const float* __restrict__ c11_w, const float* __restrict__ c11_b,
    const float* __restrict__ c12_w, const float* __restrict__ c12_b,
    const float* __restrict__ lse1_w, const float* __restrict__ lse1_b,
    const float* __restrict__ lse2_w, const float* __restrict__ lse2_b,
    const float* __restrict__ ln1_g, const float* __restrict__ ln1_b,
    const float* __restrict__ ln2_g, const float* __restrict__ ln2_b,
    const float* __restrict__ mlp1_w, const float* __restrict__ mlp1_b,
    const float* __restrict__ mlp2_w, const float* __restrict__ mlp2_b,
    const float* __restrict__ aln_g, const float* __restrict__ aln_b,
    const float* __restrict__ qkv_w, const float* __restrict__ qkv_b,
    const float* __restrict__ proj_w, const float* __restrict__ proj_b,
    const float* __restrict__ relpos,
    const float* __restrict__ fln_g, const float* __restrict__ fln_b,
    const float* __restrict__ ff1_w, const float* __restrict__ ff1_b,
    const float* __restrict__ ff2_w, const float* __restrict__ ff2_b,
    float* __restrict__ out)
{
    // ---- phase-aliased LDS pool: 9664 floats = 38656 B -> 4 blocks/CU ----
    __shared__ float pool[9664];
    float* const s_h   = pool;            // 1088  residual h (live whole kernel)
    float* const s_z   = pool + 1088;     // 1088  transformer stream
    float* const s_a   = pool + 2176;     // 1088  LN out  (phase-alias: conv temp)
    float* const s_q   = pool + 3264;     // 1088  (phase-alias: x^T [0:2112], concat)
    float* const s_k   = pool + 4352;     // 1088
    float* const s_v   = pool + 5440;     // 1088
    float* const s_fh  = pool + 6528;     // 2112  ff-half / c11-out / attn-o+att / res
    float* const s_cx  = pool + 8640;     // 1024  conv branch [c][l] (live whole kernel)
    float* const s_xt  = s_q;             // phase 0: x^T [16][SX] (2112 <= q+k = 2176)
    float* const s_y   = s_fh;            // phase 0: c11 out [16][SX]
    float* const s_t1  = s_a;             // conv temp [64][16] (1024 <= 1088)
    float* const s_o   = s_fh;            // attn out [16][SA]
    float* const s_att = s_fh + 1088;     // attn probs [16][16]
    float* const s_cat = s_q;             // final concat [16][SX]
    float* const s_res = s_fh;            // final res [16][SX]

    const int tid = threadIdx.x;
    const int b = blockIdx.x;
    const float* xb = x + (size_t)b * 2048;

    // ---- load x transposed ----
#pragma unroll
    for (int it = 0; it < 8; ++it) {
        const int idx = tid + it*256;           // = c*16 + l
        const int c = idx >> 4, l = idx & 15;
        s_xt[l*SX + c] = xb[idx];
    }
    __syncthreads();

    // ---- c11 (1x1 conv = 128x128 matmul) + relu ----
    gemm_nd<2,128,128,SX,SX,2>(s_xt, c11_w, c11_b, s_y, tid, 1, false);
    __syncthreads();

    // ---- split: conv_x [c][l], h [l][d] ----
#pragma unroll
    for (int it = 0; it < 4; ++it) {
        const int idx = tid + it*256;           // 0..1023
        const int i = idx & 63, l = idx >> 6;
        s_cx[i*16 + l] = s_y[l*SX + i];
        s_h [l*SA + i] = s_y[l*SX + 64 + i];
    }
    __syncthreads();

    // ---- conv branch ----
    conv3_lrelu(s_cx, s_t1, lse1_w, lse1_b, tid, 0, nullptr);
    __syncthreads();
    conv3_lrelu(s_t1, nullptr, lse2_w, lse2_b, tid, 1, s_cx);
    __syncthreads();

    // ---- z = LN(h, ln1) ----
    ln16x64(s_h, s_z, ln1_g, ln1_b, tid, false);
    __syncthreads();

    // ---- transformer layers ----
    for (int layer = 0; layer < 2; ++layer) {
        const float* qkv_wl  = qkv_w + (size_t)layer * 1536 * 64;
        const float* qkv_bl  = qkv_b + layer * 1536;
        const float* proj_wl = proj_w + (size_t)layer * 64 * 512;
        const float* proj_bl = proj_b + layer * 64;
        const float* rel_l   = relpos + layer * 8 * 49;

        // a = roll(LN(z, aln), -8)
        ln16x64(s_z, s_a, aln_g + layer*64, aln_b + layer*64, tid, true);
        __syncthreads();

        for (int hh = 0; hh < 8; ++hh) {
            gemm_nd<1,64,64,SA,SA,4>(s_a, qkv_wl + (size_t)(hh*64)*64,        qkv_bl + hh*64,        s_q, tid, 0, false);
            gemm_nd<1,64,64,SA,SA,4>(s_a, qkv_wl + (size_t)(512 + hh*64)*64,  qkv_bl + 512 + hh*64,  s_k, tid, 0, false);
            gemm_nd<1,64,64,SA,SA,4>(s_a, qkv_wl + (size_t)(1024 + hh*64)*64, qkv_bl + 1024 + hh*64, s_v, tid, 0, false);
            __syncthreads();

            {   // dots + relpos + mask + softmax (thread (i,j) holds one score)
                const int i = tid >> 4, j = tid & 15;
                const float* qi = s_q + i*SA;
                const float* kj = s_k + j*SA;
                float dot = 0.f;
#pragma unroll 4
                for (int d0 = 0; d0 < 64; d0 += 4) {
                    const float4 qv = *(const float4*)(qi + d0);
                    const float4 kv = *(const float4*)(kj + d0);
                    dot += qv.x*kv.x + qv.y*kv.y + qv.z*kv.z + qv.w*kv.w;
                }
                float val = dot * 0.125f
                          + rel_l[hh*49 + ((i>>2) - (j>>2) + 3)*7 + ((i&3) - (j&3) + 3)];
                const bool masked = ((hh >= 6) && (((i>>2) < 2) != ((j>>2) < 2)))
                                 || ((hh & 1) && (((i&3) < 2) != ((j&3) < 2)));
                if (masked) val = -1e9f;
                float mx = val;
#pragma unroll
                for (int m = 1; m < 16; m <<= 1) mx = fmaxf(mx, __shfl_xor(mx, m, 64));
                const float e = expf(val - mx);
                float ssum = e;
#pragma unroll
                for (int m = 1; m < 16; m <<= 1) ssum += __shfl_xor(ssum, m, 64);
                s_att[i*16 + j] = e / ssum;
            }
            __syncthreads();

            {   // out_h = attn @ v
                const int l = tid & 15, dq = tid >> 4;
                float a0 = 0.f, a1 = 0.f, a2 = 0.f, a3 = 0.f;
#pragma unroll 4
                for (int j = 0; j < 16; ++j) {
                    const float at = s_att[l*16 + j];
                    const float4 v4 = *(const float4*)(s_v + j*SA + dq*4);
                    a0 += at*v4.x; a1 += at*v4.y; a2 += at*v4.z; a3 += at*v4.w;
                }
                float* op = s_o + l*SA + dq*4;
                op[0] = a0; op[1] = a1; op[2] = a2; op[3] = a3;
            }
            __syncthreads();

            // z += o @ proj_slice^T (bias on first head only)
            gemm_nd<1,64,512,SA,SA,4>(s_o, proj_wl + hh*64,
                                      (hh == 0) ? proj_bl : nullptr, s_z, tid, 0, true);
            __syncthreads();
        }

        // FF block: two 128-col passes through s_fh
        ln16x64(s_z, s_a, fln_g + layer*64, fln_b + layer*64, tid, false);
        __syncthreads();
#pragma unroll
        for (int p = 0; p < 2; ++p) {
            gemm_nd<2,64,64,SA,SX,2>(s_a, ff1_w + (size_t)layer*256*64 + (size_t)p*128*64,
                                     ff1_b + layer*256 + p*128, s_fh, tid, 2, false);
            __syncthreads();
            gemm_nd<1,128,256,SX,SA,4>(s_fh, ff2_w + (size_t)layer*64*256 + p*128,
                                       (p == 0) ? (ff2_b + layer*64) : nullptr, s_z, tid, 0, true);
            __syncthreads();
        }
    }

    // ---- h += z; mlp block on h (two 128-col passes) ----
#pragma unroll
    for (int it = 0; it < 4; ++it) {
        const int idx = tid + it*256;
        const int d = idx & 63, l = idx >> 6;
        s_h[l*SA + d] += s_z[l*SA + d];
    }
    __syncthreads();
    ln16x64(s_h, s_a, ln2_g, ln2_b, tid, false);
    __syncthreads();
#pragma unroll
    for (int p = 0; p < 2; ++p) {
        gemm_nd<2,64,64,SA,SX,2>(s_a, mlp1_w + (size_t)p*128*64, mlp1_b + p*128, s_fh, tid, 2, false);
        __syncthreads();
        gemm_nd<1,128,256,SX,SA,4>(s_fh, mlp2_w + p*128,
                                   (p == 0) ? mlp2_b : nullptr, s_h, tid, 0, true);
        __syncthreads();
    }

    // ---- concat [conv_x ; h^T] into s_cat [l][i] ----
#pragma unroll
    for (int it = 0; it < 8; ++it) {
        const int idx = tid + it*256;           // 0..2047
        const int i = idx & 127, l = idx >> 7;
        s_cat[l*SX + i] = (i < 64) ? s_cx[i*16 + l] : s_h[l*SA + (i - 64)];
    }
    __syncthreads();

    // ---- c12 (1x1 conv) -> s_res [l][c] ----
    gemm_nd<2,128,128,SX,SX,2>(s_cat, c12_w, c12_b, s_res, tid, 0, false);
    __syncthreads();

    // ---- out = x + res (x reloaded from global) ----
    float* ob = out + (size_t)b * 2048;
#pragma unroll
    for (int it = 0; it < 8; ++it) {
        const int idx = tid + it*256;           // = c*16 + l
        const int c = idx >> 4, l = idx & 15;
        ob[idx] = xb[idx] + s_res[l*SX + c];
    }
}

extern "C" void kernel_launch(void* const* d_in, const int* in_sizes, int n_in,
                              void* d_out, int out_size, void* d_ws, size_t ws_size,
                              hipStream_t stream)
{
    const float* x      = (const float*)d_in[0];
    const float* c11_w  = (const float*)d_in[1];
    const float* c11_b  = (const float*)d_in[2];
    const float* c12_w  = (const float*)d_in[3];
    const float* c12_b  = (const float*)d_in[4];
    const float* lse1_w = (const float*)d_in[5];
    const float* lse1_b = (const float*)d_in[6];
    const float* lse2_w = (const float*)d_in[7];
    const float* lse2_b = (const float*)d_in[8];
    const float* ln1_g  = (const float*)d_in[9];
    const float* ln1_b  = (const float*)d_in[10];
    const float* ln2_g  = (const float*)d_in[11];
    const float* ln2_b  = (const float*)d_in[12];
    const float* mlp1_w = (const float*)d_in[13];
    const float* mlp1_b = (const float*)d_in[14];
    const float* mlp2_w = (const float*)d_in[15];
    const float* mlp2_b = (const float*)d_in[16];
    const float* aln_g  = (const float*)d_in[17];
    const float* aln_b  = (const float*)d_in[18];
    const float* qkv_w  = (const float*)d_in[19];
    const float* qkv_b  = (const float*)d_in[20];
    const float* proj_w = (const float*)d_in[21];
    const float* proj_b = (const float*)d_in[22];
    const float* relpos = (const float*)d_in[23];
    const float* fln_g  = (const float*)d_in[24];
    const float* fln_b  = (const float*)d_in[25];
    const float* ff1_w  = (const float*)d_in[26];
    const float* ff1_b  = (const float*)d_in[27];
    const float* ff2_w  = (const float*)d_in[28];
    const float* ff2_b  = (const float*)d_in[29];

    const int B = in_sizes[0] / (128 * 16);

    vse_fused<<<dim3(B), dim3(256), 0, stream>>>(
        x, c11_w, c11_b, c12_w, c12_b, lse1_w, lse1_b, lse2_w, lse2_b,
        ln1_g, ln1_b, ln2_g, ln2_b, mlp1_w, mlp1_b, mlp2_w, mlp2_b,
        aln_g, aln_b, qkv_w, qkv_b, proj_w, proj_b, relpos,
        fln_g, fln_b, ff1_w, ff1_b, ff2_w, ff2_b,
        (float*)d_out);
}